// Round 1
// baseline (263.305 us; speedup 1.0000x reference)
//
#include <hip/hip_runtime.h>

// Problem constants
#define NB 4      // batch
#define CI 256    // input channels
#define HH 64
#define WW 64
#define MC 64     // compressed channels
#define HS 128    // H*2
#define WS_ 128   // W*2
#define HW 4096   // HH*WW

// ---------------------------------------------------------------------------
// Kernel 1: 1x1 conv  x(4,256,64,64) * w_comp(64,256) -> comp(4,64,64,64)
// grid (64 pixel-blocks, 4 m-groups), block 256. Weights read via uniform
// (scalar) loads; 16 independent accumulators per thread.
// ---------------------------------------------------------------------------
__global__ __launch_bounds__(256) void conv1x1_kernel(
    const float* __restrict__ x, const float* __restrict__ w_comp,
    const float* __restrict__ b_comp, float* __restrict__ comp) {
  int tid = threadIdx.x;
  int mg  = blockIdx.y;                 // 4 groups of 16 output channels
  int pix = blockIdx.x * 256 + tid;     // 0..16383
  int n = pix >> 12, hw = pix & 4095;
  const float* xp = x + n * CI * HW + hw;
  const float* wp = w_comp + mg * 16 * 256;   // uniform base
  float acc[16];
#pragma unroll
  for (int m = 0; m < 16; ++m) acc[m] = b_comp[mg * 16 + m];
  for (int c = 0; c < 256; ++c) {
    float xv = xp[c * HW];
#pragma unroll
    for (int m = 0; m < 16; ++m) acc[m] = fmaf(xv, wp[m * 256 + c], acc[m]);
  }
  float* cp = comp + (n * MC + mg * 16) * HW + hw;
#pragma unroll
  for (int m = 0; m < 16; ++m) cp[m * HW] = acc[m];
}

// ---------------------------------------------------------------------------
// Kernel 2: 3x3 conv (64->100) fused with pixel-shuffle + softmax(25).
// Block owns (n, q, 16x16 tile); q = sh*2+sw selects output channels
// o = kk*4+q. Input tile double-buffered global->reg->LDS. Weights are
// wave-uniform -> scalar loads feeding v_fmac SGPR operand.
// Writes softmaxed weights to wbuf layout (n, y, x, 25).
// ---------------------------------------------------------------------------
__global__ __launch_bounds__(256) void kenc_kernel(
    const float* __restrict__ comp, const float* __restrict__ w_enc,
    const float* __restrict__ b_enc, float* __restrict__ wbuf) {
  __shared__ float ctile[2][324];       // 18x18 halo tile, double buffered
  int tid = threadIdx.x;
  int q = blockIdx.y, n = blockIdx.z;
  int th0 = (blockIdx.x >> 2) << 4, tw0 = (blockIdx.x & 3) << 4;
  int ty = tid >> 4, tx = tid & 15;

  // Precompute staging coords for elements tid and tid+256
  int i0 = tid, i1 = tid + 256;
  int r0 = i0 / 18, c0 = i0 - r0 * 18;
  int r1 = i1 / 18, c1 = i1 - r1 * 18;
  int gh0 = th0 - 1 + r0, gw0 = tw0 - 1 + c0;
  int gh1 = th0 - 1 + r1, gw1 = tw0 - 1 + c1;
  bool v0 = ((unsigned)gh0 < 64u) && ((unsigned)gw0 < 64u);
  bool v1 = (i1 < 324) && ((unsigned)gh1 < 64u) && ((unsigned)gw1 < 64u);
  const float* cbase = comp + n * MC * HW;
  int off0 = gh0 * 64 + gw0, off1 = gh1 * 64 + gw1;

  float p0 = v0 ? cbase[off0] : 0.f;
  float p1 = v1 ? cbase[off1] : 0.f;

  float acc[25];
#pragma unroll
  for (int kk = 0; kk < 25; ++kk) acc[kk] = b_enc[kk * 4 + q];

  for (int m = 0; m < 64; ++m) {
    int buf = m & 1;
    ctile[buf][i0] = p0;
    if (i1 < 324) ctile[buf][i1] = p1;
    __syncthreads();
    if (m < 63) {                       // prefetch next plane (issue early)
      p0 = v0 ? cbase[(m + 1) * HW + off0] : 0.f;
      p1 = v1 ? cbase[(m + 1) * HW + off1] : 0.f;
    }
    const float* wp = w_enc + q * 576 + m * 9;   // uniform; +kk*2304 +dy*3+dx
#pragma unroll
    for (int dy = 0; dy < 3; ++dy)
#pragma unroll
      for (int dx = 0; dx < 3; ++dx) {
        float v = ctile[buf][(ty + dy) * 18 + tx + dx];
#pragma unroll
        for (int kk = 0; kk < 25; ++kk)
          acc[kk] = fmaf(v, wp[kk * 2304 + dy * 3 + dx], acc[kk]);
      }
    __syncthreads();
  }

  // softmax over the 25 taps (in-register)
  float mx = acc[0];
#pragma unroll
  for (int kk = 1; kk < 25; ++kk) mx = fmaxf(mx, acc[kk]);
  float s = 0.f;
#pragma unroll
  for (int kk = 0; kk < 25; ++kk) { acc[kk] = __expf(acc[kk] - mx); s += acc[kk]; }
  float inv = 1.f / s;

  int oy = 2 * (th0 + ty) + (q >> 1);
  int ox = 2 * (tw0 + tx) + (q & 1);
  float* op = wbuf + ((n * HS + oy) * WS_ + ox) * 25;
#pragma unroll
  for (int kk = 0; kk < 25; ++kk) op[kk] = acc[kk] * inv;
}

// ---------------------------------------------------------------------------
// Kernel 3: reassembly. Block = 8x8 output tile (4x4 input pixels), all 256
// channels staged in LDS (8x8 patch per channel, XOR-swizzled planes).
// Thread = 1x4 output quad x 16 channels; 100 weight VGPRs; float4 stores.
// ---------------------------------------------------------------------------
__global__ __launch_bounds__(256) void reassembly_kernel(
    const float* __restrict__ x, const float* __restrict__ wbuf,
    float* __restrict__ out) {
  __shared__ float xpatch[256 * 64];    // [c][r*8+cc], swizzled cc ^= 2*(c&3)
  int tid = threadIdx.x;
  int n = blockIdx.y;
  int tile = blockIdx.x;                // 16x16 tiles of 8x8 outputs
  int ty0 = (tile >> 4) << 3, tx0 = (tile & 15) << 3;
  int h0 = ty0 >> 1, w0 = tx0 >> 1;

  // stage 256ch x 8x8 patch, zero-padded, swizzled
  for (int i = tid; i < 16384; i += 256) {
    int c = i >> 6, pos = i & 63;
    int r = pos >> 3, cc = pos & 7;
    int gh = h0 - 2 + r, gw = w0 - 2 + cc;
    float v = 0.f;
    if (((unsigned)gh < 64u) && ((unsigned)gw < 64u))
      v = x[((n * CI + c) * HH + gh) * WW + gw];
    int sw = ((c & 3) << 1);
    xpatch[(i & ~7) | ((i & 7) ^ sw)] = v;
  }
  __syncthreads();

  int cslot = tid >> 4;                 // 0..15
  int quad  = tid & 15;                 // 0..15 : (qy 0..7, qx 0..1)
  int qy = quad >> 1, qx = quad & 1;
  int oy = ty0 + qy;
  int hl = qy >> 1;                     // local input row
  int ox0 = tx0 + qx * 4;
  int ix0 = qx * 2;                     // local input col of first pair

  // 100 weights: 4 adjacent output pixels x 25, contiguous in wbuf
  float wreg[100];
  const float* wp = wbuf + ((n * HS + oy) * WS_ + ox0) * 25;
#pragma unroll
  for (int k = 0; k < 100; ++k) wreg[k] = wp[k];

  int s = ((cslot & 3) << 1);           // c&3 == cslot&3 for c = it*16+cslot
  int b0 = (ix0 + 0) ^ s, b2 = (ix0 + 2) ^ s, b4 = (ix0 + 4) ^ s;

  for (int it = 0; it < 16; ++it) {
    int c = it * 16 + cslot;
    const float* p = xpatch + c * 64;
    float a0 = 0.f, a1 = 0.f, a2 = 0.f, a3 = 0.f;
#pragma unroll
    for (int i = 0; i < 5; ++i) {
      const float* row = p + (hl + i) * 8;
      float2 f01 = *(const float2*)(row + b0);
      float2 f23 = *(const float2*)(row + b2);
      float2 f45 = *(const float2*)(row + b4);
      float f[6] = {f01.x, f01.y, f23.x, f23.y, f45.x, f45.y};
#pragma unroll
      for (int j = 0; j < 5; ++j) {
        a0 = fmaf(f[j],     wreg[i * 5 + j],      a0);
        a1 = fmaf(f[j],     wreg[25 + i * 5 + j], a1);
        a2 = fmaf(f[j + 1], wreg[50 + i * 5 + j], a2);
        a3 = fmaf(f[j + 1], wreg[75 + i * 5 + j], a3);
      }
    }
    float4 o4 = make_float4(a0, a1, a2, a3);
    *(float4*)(out + (size_t)((n * CI + c) * HS + oy) * WS_ + ox0) = o4;
  }
}

// ---------------------------------------------------------------------------
extern "C" void kernel_launch(void* const* d_in, const int* in_sizes, int n_in,
                              void* d_out, int out_size, void* d_ws,
                              size_t ws_size, hipStream_t stream) {
  const float* x      = (const float*)d_in[0];
  const float* w_comp = (const float*)d_in[1];
  const float* b_comp = (const float*)d_in[2];
  const float* w_enc  = (const float*)d_in[3];
  const float* b_enc  = (const float*)d_in[4];
  float* out = (float*)d_out;

  float* comp = (float*)d_ws;                    // 4*64*4096   = 1,048,576 f
  float* wbuf = comp + NB * MC * HW;             // 4*128*128*25= 1,638,400 f

  conv1x1_kernel<<<dim3(64, 4), 256, 0, stream>>>(x, w_comp, b_comp, comp);
  kenc_kernel<<<dim3(16, 4, 4), 256, 0, stream>>>(comp, w_enc, b_enc, wbuf);
  reassembly_kernel<<<dim3(256, 4), 256, 0, stream>>>(x, wbuf, out);
}

// Round 2
// 121.672 us; speedup vs baseline: 2.1641x; 2.1641x over previous
//
#include <hip/hip_runtime.h>

// Problem constants
#define NB 4      // batch
#define CI 256    // input channels
#define HH 64
#define WW 64
#define MC 64     // compressed channels
#define HS 128    // H*2
#define WS_ 128   // W*2
#define HW 4096   // HH*WW

typedef __attribute__((ext_vector_type(8))) short short8v;   // 8 bf16 (4 VGPRs)
typedef __attribute__((ext_vector_type(4))) float floatx4;   // MFMA C/D

__device__ inline unsigned short f2bf(float f) {
  union { float f; unsigned u; } v; v.f = f;
  unsigned r = v.u + 0x7FFFu + ((v.u >> 16) & 1u);   // RNE
  return (unsigned short)(r >> 16);
}

// ---------------------------------------------------------------------------
// Prep: rearrange weights into MFMA A-fragment layout (bf16).
// Aw1[ks][o:64][kl:32]  = w_comp[o][ks*32+kl]                (8 k-steps)
// Aw2[ks][o:112][kl:32] = w_enc[o][m][tap], tap=ks>>1, m=(ks&1)*32+kl
//                         (18 k-steps; o>=100 zero-padded)
// ---------------------------------------------------------------------------
__global__ __launch_bounds__(256) void prep_kernel(
    const float* __restrict__ w_comp, const float* __restrict__ w_enc,
    unsigned short* __restrict__ Aw1, unsigned short* __restrict__ Aw2) {
  int i = blockIdx.x * 256 + threadIdx.x;
  if (i < 16384) {                       // 8*64*32
    int kl = i & 31, o = (i >> 5) & 63, ks = i >> 11;
    Aw1[i] = f2bf(w_comp[o * 256 + ks * 32 + kl]);
  } else if (i < 16384 + 64512) {        // 18*112*32
    int j = i - 16384;
    int kl = j & 31, o = (j >> 5) % 112, ks = (j >> 5) / 112;
    int t = ks >> 1, m = (ks & 1) * 32 + kl;
    Aw2[j] = (o < 100) ? f2bf(w_enc[o * 576 + m * 9 + t]) : (unsigned short)0;
  }
}

// ---------------------------------------------------------------------------
// Kernel 1: 1x1 conv via MFMA.  C[o][pix] = sum_c w_comp[o][c] * x[c][pix]
// Wave = 16 pixels (N-tile), 4 o-tiles, K=256 (8 k-steps of 32).
// Output: comp_cl bf16 channel-last [n][pix:4096][o:64].
// ---------------------------------------------------------------------------
__global__ __launch_bounds__(256, 1) void conv1x1_mfma(
    const float* __restrict__ x, const unsigned short* __restrict__ Aw1,
    const float* __restrict__ b_comp, unsigned short* __restrict__ comp_cl) {
  int tid = threadIdx.x;
  int wid = tid >> 6, lane = tid & 63;
  int Nt = blockIdx.x * 4 + wid;          // 0..1023
  int n = Nt >> 8, pixbase = (Nt & 255) * 16;
  int l15 = lane & 15, g = lane >> 4;
  int pix = pixbase + l15;

  floatx4 acc[4];
#pragma unroll
  for (int ot = 0; ot < 4; ++ot) acc[ot] = (floatx4){0.f, 0.f, 0.f, 0.f};

  const float* xb = x + (size_t)n * CI * HW + pix;
  const unsigned short* ab = Aw1 + l15 * 32 + g * 8;

#pragma unroll
  for (int ks = 0; ks < 8; ++ks) {
    // B fragment: 8 consecutive channels at this pixel (fp32 -> bf16)
    int c0 = ks * 32 + g * 8;
    short8v bfrag;
#pragma unroll
    for (int j = 0; j < 8; ++j)
      bfrag[j] = (short)f2bf(xb[(size_t)(c0 + j) * HW]);
#pragma unroll
    for (int ot = 0; ot < 4; ++ot) {
      short8v af = *(const short8v*)(ab + (ks * 64 + ot * 16) * 32);
      acc[ot] = __builtin_amdgcn_mfma_f32_16x16x32_bf16(af, bfrag, acc[ot], 0, 0, 0);
    }
  }

  // Epilogue: bias, bf16, store channel-last.  row o = ot*16+g*4+r, col pix.
  unsigned short* cp = comp_cl + ((size_t)(n * HW + pix)) * 64;
#pragma unroll
  for (int ot = 0; ot < 4; ++ot) {
    const float4 bv = *(const float4*)(b_comp + ot * 16 + g * 4);
    unsigned h01 = (unsigned)f2bf(acc[ot][0] + bv.x) |
                   ((unsigned)f2bf(acc[ot][1] + bv.y) << 16);
    unsigned h23 = (unsigned)f2bf(acc[ot][2] + bv.z) |
                   ((unsigned)f2bf(acc[ot][3] + bv.w) << 16);
    *(int2*)(cp + ot * 16 + g * 4) = make_int2((int)h01, (int)h23);
  }
}

// ---------------------------------------------------------------------------
// Kernel 2: 3x3 conv (64->100) + pixel-shuffle + softmax(25) via MFMA.
// C[o][pix] = sum_{m,tap} w_enc[o][m][tap] * comp[m][pix+shift(tap)]
// K = tap*64+m (tap-major), 18 k-steps.  7 o-tiles (M=112, zero-padded).
// Per-pixel softmax over kk=0..24 where o = kk*4+q, q = o&3:
//   lane holds o = ot*16 + g*4 + r  ->  q=r, kk = ot*4+g  -> reduce over
//   ot (in-lane) and g (shfl_xor 16,32).
// Output: wbuf_q fp32 [n][q:4][pix:4096][kk:25].
// ---------------------------------------------------------------------------
__global__ __launch_bounds__(256, 1) void kenc_mfma(
    const unsigned short* __restrict__ comp_cl,
    const unsigned short* __restrict__ Aw2,
    const float* __restrict__ b_enc, float* __restrict__ wbuf_q) {
  int tid = threadIdx.x;
  int wid = tid >> 6, lane = tid & 63;
  int Nt = blockIdx.x * 4 + wid;          // 0..1023
  int n = Nt >> 8, pixbase = (Nt & 255) * 16;
  int l15 = lane & 15, g = lane >> 4;
  int pix = pixbase + l15;
  int y = pix >> 6, xcol = pix & 63;

  // Per-lane tap masks and pixel shifts
  bool vm[9];
  int sh9[9];
#pragma unroll
  for (int t = 0; t < 9; ++t) {
    int dy = t / 3, dx = t % 3;
    vm[t] = ((unsigned)(y + dy - 1) < 64u) && ((unsigned)(xcol + dx - 1) < 64u);
    sh9[t] = (dy - 1) * 64 + (dx - 1);
  }

  floatx4 acc[7];
#pragma unroll
  for (int ot = 0; ot < 7; ++ot) acc[ot] = (floatx4){0.f, 0.f, 0.f, 0.f};

  const unsigned short* cb = comp_cl + (size_t)n * HW * 64;
  const unsigned short* ab = Aw2 + l15 * 32 + g * 8;
  const short8v zv = {0, 0, 0, 0, 0, 0, 0, 0};

#pragma unroll
  for (int ks = 0; ks < 18; ++ks) {
    int t = ks >> 1, mh = ks & 1;
    const unsigned short* bp = cb + (pix + sh9[t]) * 64 + mh * 32 + g * 8;
    short8v bfrag = vm[t] ? *(const short8v*)bp : zv;
#pragma unroll
    for (int ot = 0; ot < 7; ++ot) {
      short8v af = *(const short8v*)(ab + (ks * 112 + ot * 16) * 32);
      acc[ot] = __builtin_amdgcn_mfma_f32_16x16x32_bf16(af, bfrag, acc[ot], 0, 0, 0);
    }
  }

  // bias (b_enc has 100 entries; clamp base for padded rows -- excluded later)
#pragma unroll
  for (int ot = 0; ot < 7; ++ot) {
    int ob = ot * 16 + g * 4; if (ob > 96) ob = 96;
    const float4 bv = *(const float4*)(b_enc + ob);
    acc[ot][0] += bv.x; acc[ot][1] += bv.y; acc[ot][2] += bv.z; acc[ot][3] += bv.w;
  }

  // softmax over kk = ot*4+g (valid kk<25: ot<6 always, ot==6 only g==0)
#pragma unroll
  for (int r = 0; r < 4; ++r) {
    float m = acc[0][r];
#pragma unroll
    for (int ot = 1; ot < 6; ++ot) m = fmaxf(m, acc[ot][r]);
    if (g == 0) m = fmaxf(m, acc[6][r]);
    m = fmaxf(m, __shfl_xor(m, 16));
    m = fmaxf(m, __shfl_xor(m, 32));
    float s = 0.f;
    float e[7];
#pragma unroll
    for (int ot = 0; ot < 7; ++ot) {
      bool val = (ot < 6) || (g == 0);
      e[ot] = val ? __expf(acc[ot][r] - m) : 0.f;
      s += e[ot];
    }
    s += __shfl_xor(s, 16);
    s += __shfl_xor(s, 32);
    float inv = 1.f / s;
    float* wq = wbuf_q + ((size_t)(n * 4 + r) * HW + pix) * 25;
#pragma unroll
    for (int ot = 0; ot < 7; ++ot)
      if ((ot < 6) || (g == 0)) wq[ot * 4 + g] = e[ot] * inv;
  }
}

// ---------------------------------------------------------------------------
// Kernel 3: reassembly (unchanged math; wbuf now q-planar [n][q][pix][25]).
// ---------------------------------------------------------------------------
__global__ __launch_bounds__(256) void reassembly_kernel(
    const float* __restrict__ x, const float* __restrict__ wbuf,
    float* __restrict__ out) {
  __shared__ float xpatch[256 * 64];    // [c][r*8+cc], swizzled cc ^= 2*(c&3)
  int tid = threadIdx.x;
  int n = blockIdx.y;
  int tile = blockIdx.x;                // 16x16 tiles of 8x8 outputs
  int ty0 = (tile >> 4) << 3, tx0 = (tile & 15) << 3;
  int h0 = ty0 >> 1, w0 = tx0 >> 1;

  // stage 256ch x 8x8 patch, zero-padded, swizzled
  for (int i = tid; i < 16384; i += 256) {
    int c = i >> 6, pos = i & 63;
    int r = pos >> 3, cc = pos & 7;
    int gh = h0 - 2 + r, gw = w0 - 2 + cc;
    float v = 0.f;
    if (((unsigned)gh < 64u) && ((unsigned)gw < 64u))
      v = x[((n * CI + c) * HH + gh) * WW + gw];
    int sw = ((c & 3) << 1);
    xpatch[(i & ~7) | ((i & 7) ^ sw)] = v;
  }
  __syncthreads();

  int cslot = tid >> 4;                 // 0..15
  int quad  = tid & 15;                 // 0..15 : (qy 0..7, qx 0..1)
  int qy = quad >> 1, qx = quad & 1;
  int oy = ty0 + qy;
  int hl = qy >> 1;                     // local input row
  int ox0 = tx0 + qx * 4;
  int ix0 = qx * 2;                     // local input col of first pair

  // 100 weights for 4 adjacent output pixels, from q-planar wbuf
  int sh = qy & 1;
  int xA = ox0 >> 1;
  int ysrc = oy >> 1;
  const float* wq0 = wbuf + ((size_t)(n * 4 + sh * 2 + 0) * HW + ysrc * 64 + xA) * 25;
  const float* wq1 = wbuf + ((size_t)(n * 4 + sh * 2 + 1) * HW + ysrc * 64 + xA) * 25;
  float wreg[100];
#pragma unroll
  for (int k = 0; k < 25; ++k) {
    wreg[k]      = wq0[k];        // pixel ox0+0: (q=sh*2,   x=xA)
    wreg[25 + k] = wq1[k];        // pixel ox0+1: (q=sh*2+1, x=xA)
    wreg[50 + k] = wq0[25 + k];   // pixel ox0+2: (q=sh*2,   x=xA+1)
    wreg[75 + k] = wq1[25 + k];   // pixel ox0+3: (q=sh*2+1, x=xA+1)
  }

  int s = ((cslot & 3) << 1);           // c&3 == cslot&3 for c = it*16+cslot
  int b0 = (ix0 + 0) ^ s, b2 = (ix0 + 2) ^ s, b4 = (ix0 + 4) ^ s;

  for (int it = 0; it < 16; ++it) {
    int c = it * 16 + cslot;
    const float* p = xpatch + c * 64;
    float a0 = 0.f, a1 = 0.f, a2 = 0.f, a3 = 0.f;
#pragma unroll
    for (int i = 0; i < 5; ++i) {
      const float* row = p + (hl + i) * 8;
      float2 f01 = *(const float2*)(row + b0);
      float2 f23 = *(const float2*)(row + b2);
      float2 f45 = *(const float2*)(row + b4);
      float f[6] = {f01.x, f01.y, f23.x, f23.y, f45.x, f45.y};
#pragma unroll
      for (int j = 0; j < 5; ++j) {
        a0 = fmaf(f[j],     wreg[i * 5 + j],      a0);
        a1 = fmaf(f[j],     wreg[25 + i * 5 + j], a1);
        a2 = fmaf(f[j + 1], wreg[50 + i * 5 + j], a2);
        a3 = fmaf(f[j + 1], wreg[75 + i * 5 + j], a3);
      }
    }
    float4 o4 = make_float4(a0, a1, a2, a3);
    *(float4*)(out + (size_t)((n * CI + c) * HS + oy) * WS_ + ox0) = o4;
  }
}

// ---------------------------------------------------------------------------
extern "C" void kernel_launch(void* const* d_in, const int* in_sizes, int n_in,
                              void* d_out, int out_size, void* d_ws,
                              size_t ws_size, hipStream_t stream) {
  const float* x      = (const float*)d_in[0];
  const float* w_comp = (const float*)d_in[1];
  const float* b_comp = (const float*)d_in[2];
  const float* w_enc  = (const float*)d_in[3];
  const float* b_enc  = (const float*)d_in[4];
  float* out = (float*)d_out;

  char* ws = (char*)d_ws;
  unsigned short* comp_cl = (unsigned short*)ws;                  // 2,097,152 B
  unsigned short* Aw1     = (unsigned short*)(ws + 2097152);      //    32,768 B
  unsigned short* Aw2     = (unsigned short*)(ws + 2129920);      //   129,024 B
  float*          wbuf_q  = (float*)(ws + 2359296);               // 6,553,600 B

  prep_kernel<<<dim3(316), 256, 0, stream>>>(w_comp, w_enc, Aw1, Aw2);
  conv1x1_mfma<<<dim3(256), 256, 0, stream>>>(x, Aw1, b_comp, comp_cl);
  kenc_mfma<<<dim3(256), 256, 0, stream>>>(comp_cl, Aw2, b_enc, wbuf_q);
  reassembly_kernel<<<dim3(256, 4), 256, 0, stream>>>(x, wbuf_q, out);
}

// Round 3
// 75.910 us; speedup vs baseline: 3.4686x; 1.6028x over previous
//
#include <hip/hip_runtime.h>

// Problem constants
#define NB 4      // batch
#define CI 256    // input channels
#define HH 64
#define WW 64
#define MC 64     // compressed channels
#define HS 128    // H*2
#define WS_ 128   // W*2
#define HW 4096   // HH*WW

typedef __attribute__((ext_vector_type(8))) short short8v;   // 8 bf16 (4 VGPRs)
typedef __attribute__((ext_vector_type(4))) float floatx4;   // MFMA C/D

__device__ inline unsigned short f2bf(float f) {
  union { float f; unsigned u; } v; v.f = f;
  unsigned r = v.u + 0x7FFFu + ((v.u >> 16) & 1u);   // RNE
  return (unsigned short)(r >> 16);
}

// ---------------------------------------------------------------------------
// Prep: rearrange weights into MFMA A-fragment layout (bf16).
// Aw1[ks][o:64][kl:32]  = w_comp[o][ks*32+kl]                (8 k-steps)
// Aw2[ks][o:112][kl:32] = w_enc[o][m][tap], tap=ks>>1, m=(ks&1)*32+kl
//                         (18 k-steps; o>=100 zero-padded)
// ---------------------------------------------------------------------------
__global__ __launch_bounds__(256) void prep_kernel(
    const float* __restrict__ w_comp, const float* __restrict__ w_enc,
    unsigned short* __restrict__ Aw1, unsigned short* __restrict__ Aw2) {
  int i = blockIdx.x * 256 + threadIdx.x;
  if (i < 16384) {                       // 8*64*32
    int kl = i & 31, o = (i >> 5) & 63, ks = i >> 11;
    Aw1[i] = f2bf(w_comp[o * 256 + ks * 32 + kl]);
  } else if (i < 16384 + 64512) {        // 18*112*32
    int j = i - 16384;
    int kl = j & 31, o = (j >> 5) % 112, ks = (j >> 5) / 112;
    int t = ks >> 1, m = (ks & 1) * 32 + kl;
    Aw2[j] = (o < 100) ? f2bf(w_enc[o * 576 + m * 9 + t]) : (unsigned short)0;
  }
}

// ---------------------------------------------------------------------------
// Kernel 1: 1x1 conv via MFMA.  C[o][pix] = sum_c w_comp[o][c] * x[c][pix]
// Wave = 16 pixels (N-tile), 4 o-tiles, K=256 (8 k-steps of 32).
// Output: comp_cl bf16 channel-last [n][pix:4096][o:64].
// ---------------------------------------------------------------------------
__global__ __launch_bounds__(256, 1) void conv1x1_mfma(
    const float* __restrict__ x, const unsigned short* __restrict__ Aw1,
    const float* __restrict__ b_comp, unsigned short* __restrict__ comp_cl) {
  int tid = threadIdx.x;
  int wid = tid >> 6, lane = tid & 63;
  int Nt = blockIdx.x * 4 + wid;          // 0..1023
  int n = Nt >> 8, pixbase = (Nt & 255) * 16;
  int l15 = lane & 15, g = lane >> 4;
  int pix = pixbase + l15;

  floatx4 acc[4];
#pragma unroll
  for (int ot = 0; ot < 4; ++ot) acc[ot] = (floatx4){0.f, 0.f, 0.f, 0.f};

  const float* xb = x + (size_t)n * CI * HW + pix;
  const unsigned short* ab = Aw1 + l15 * 32 + g * 8;

#pragma unroll
  for (int ks = 0; ks < 8; ++ks) {
    // B fragment: 8 consecutive channels at this pixel (fp32 -> bf16)
    int c0 = ks * 32 + g * 8;
    short8v bfrag;
#pragma unroll
    for (int j = 0; j < 8; ++j)
      bfrag[j] = (short)f2bf(xb[(size_t)(c0 + j) * HW]);
#pragma unroll
    for (int ot = 0; ot < 4; ++ot) {
      short8v af = *(const short8v*)(ab + (ks * 64 + ot * 16) * 32);
      acc[ot] = __builtin_amdgcn_mfma_f32_16x16x32_bf16(af, bfrag, acc[ot], 0, 0, 0);
    }
  }

  // Epilogue: bias, bf16, store channel-last.  row o = ot*16+g*4+r, col pix.
  unsigned short* cp = comp_cl + ((size_t)(n * HW + pix)) * 64;
#pragma unroll
  for (int ot = 0; ot < 4; ++ot) {
    const float4 bv = *(const float4*)(b_comp + ot * 16 + g * 4);
    unsigned h01 = (unsigned)f2bf(acc[ot][0] + bv.x) |
                   ((unsigned)f2bf(acc[ot][1] + bv.y) << 16);
    unsigned h23 = (unsigned)f2bf(acc[ot][2] + bv.z) |
                   ((unsigned)f2bf(acc[ot][3] + bv.w) << 16);
    *(int2*)(cp + ot * 16 + g * 4) = make_int2((int)h01, (int)h23);
  }
}

// ---------------------------------------------------------------------------
// Kernel 2: 3x3 conv (64->100) + pixel-shuffle + softmax(25) via MFMA.
// ---------------------------------------------------------------------------
__global__ __launch_bounds__(256, 1) void kenc_mfma(
    const unsigned short* __restrict__ comp_cl,
    const unsigned short* __restrict__ Aw2,
    const float* __restrict__ b_enc, float* __restrict__ wbuf_q) {
  int tid = threadIdx.x;
  int wid = tid >> 6, lane = tid & 63;
  int Nt = blockIdx.x * 4 + wid;          // 0..1023
  int n = Nt >> 8, pixbase = (Nt & 255) * 16;
  int l15 = lane & 15, g = lane >> 4;
  int pix = pixbase + l15;
  int y = pix >> 6, xcol = pix & 63;

  // Per-lane tap masks and pixel shifts
  bool vm[9];
  int sh9[9];
#pragma unroll
  for (int t = 0; t < 9; ++t) {
    int dy = t / 3, dx = t % 3;
    vm[t] = ((unsigned)(y + dy - 1) < 64u) && ((unsigned)(xcol + dx - 1) < 64u);
    sh9[t] = (dy - 1) * 64 + (dx - 1);
  }

  floatx4 acc[7];
#pragma unroll
  for (int ot = 0; ot < 7; ++ot) acc[ot] = (floatx4){0.f, 0.f, 0.f, 0.f};

  const unsigned short* cb = comp_cl + (size_t)n * HW * 64;
  const unsigned short* ab = Aw2 + l15 * 32 + g * 8;
  const short8v zv = {0, 0, 0, 0, 0, 0, 0, 0};

#pragma unroll
  for (int ks = 0; ks < 18; ++ks) {
    int t = ks >> 1, mh = ks & 1;
    const unsigned short* bp = cb + (pix + sh9[t]) * 64 + mh * 32 + g * 8;
    short8v bfrag = vm[t] ? *(const short8v*)bp : zv;
#pragma unroll
    for (int ot = 0; ot < 7; ++ot) {
      short8v af = *(const short8v*)(ab + (ks * 112 + ot * 16) * 32);
      acc[ot] = __builtin_amdgcn_mfma_f32_16x16x32_bf16(af, bfrag, acc[ot], 0, 0, 0);
    }
  }

  // bias
#pragma unroll
  for (int ot = 0; ot < 7; ++ot) {
    int ob = ot * 16 + g * 4; if (ob > 96) ob = 96;
    const float4 bv = *(const float4*)(b_enc + ob);
    acc[ot][0] += bv.x; acc[ot][1] += bv.y; acc[ot][2] += bv.z; acc[ot][3] += bv.w;
  }

  // softmax over kk = ot*4+g (valid kk<25: ot<6 always, ot==6 only g==0)
#pragma unroll
  for (int r = 0; r < 4; ++r) {
    float m = acc[0][r];
#pragma unroll
    for (int ot = 1; ot < 6; ++ot) m = fmaxf(m, acc[ot][r]);
    if (g == 0) m = fmaxf(m, acc[6][r]);
    m = fmaxf(m, __shfl_xor(m, 16));
    m = fmaxf(m, __shfl_xor(m, 32));
    float s = 0.f;
    float e[7];
#pragma unroll
    for (int ot = 0; ot < 7; ++ot) {
      bool val = (ot < 6) || (g == 0);
      e[ot] = val ? __expf(acc[ot][r] - m) : 0.f;
      s += e[ot];
    }
    s += __shfl_xor(s, 16);
    s += __shfl_xor(s, 32);
    float inv = 1.f / s;
    float* wq = wbuf_q + ((size_t)(n * 4 + r) * HW + pix) * 25;
#pragma unroll
    for (int ot = 0; ot < 7; ++ot)
      if ((ot < 6) || (g == 0)) wq[ot * 4 + g] = e[ot] * inv;
  }
}

// ---------------------------------------------------------------------------
// Kernel 3: reassembly, v2.
// Block = 4x16 output tile (2x8 input pixels) x 128 channels (cg half).
// LDS: 128 ch x 6x12 halo patch fp32, c-stride 72 floats = 36 KB ->
// 4 blocks/CU. Staging: 9 float4-slots/thread via float2 global loads
// (block-uniform interior/edge branch), consecutive-f4 ds_write_b128.
// Thread = 4 outputs (1 row x 4 cols) x 16 channels (8 iters).
// ---------------------------------------------------------------------------
__global__ __launch_bounds__(256) void reassembly_kernel(
    const float* __restrict__ x, const float* __restrict__ wbuf,
    float* __restrict__ out) {
  __shared__ float xpatch[128 * 72];    // [c][r:6][col:12]
  int tid = threadIdx.x;
  int bid = blockIdx.x;                 // tile(256) | n(4) | cg(2)
  int tile = bid & 255;
  int n = (bid >> 8) & 3;
  int cg = bid >> 10;
  int tyi = tile >> 3, txi = tile & 7;  // 32 x 8 tiles of 4x16 outputs
  int ty0 = tyi * 4, tx0 = txi * 16;
  int h0 = ty0 >> 1, w0 = tx0 >> 1;     // input block base (2 rows x 8 cols)

  const float* xb = x + (size_t)(n * CI + cg * 128) * HW;
  bool interior = (tyi >= 1) && (tyi <= 30) && (txi >= 1) && (txi <= 6);

  if (interior) {
#pragma unroll
    for (int j = 0; j < 9; ++j) {
      int f = tid + 256 * j;            // f4 index 0..2303 (128*18)
      int c = f / 18, rem = f - c * 18;
      int r = rem / 3, h = rem - r * 3;
      const float* gp = xb + (size_t)c * HW + (h0 - 2 + r) * WW + (w0 - 2 + h * 4);
      float2 lo = *(const float2*)(gp);       // 8B-aligned (gw even)
      float2 hi = *(const float2*)(gp + 2);
      *(float4*)(xpatch + c * 72 + r * 12 + h * 4) =
          make_float4(lo.x, lo.y, hi.x, hi.y);
    }
  } else {
#pragma unroll
    for (int j = 0; j < 9; ++j) {
      int f = tid + 256 * j;
      int c = f / 18, rem = f - c * 18;
      int r = rem / 3, h = rem - r * 3;
      int gh = h0 - 2 + r;
      float vv[4];
#pragma unroll
      for (int e = 0; e < 4; ++e) {
        int gw = w0 - 2 + h * 4 + e;
        vv[e] = (((unsigned)gh < 64u) && ((unsigned)gw < 64u))
                    ? xb[(size_t)c * HW + gh * WW + gw] : 0.f;
      }
      *(float4*)(xpatch + c * 72 + r * 12 + h * 4) =
          make_float4(vv[0], vv[1], vv[2], vv[3]);
    }
  }
  __syncthreads();

  int cslot = tid >> 4;                 // 0..15
  int quad  = tid & 15;                 // qy(4) x qx(4)
  int qy = quad >> 2, qx = quad & 3;
  int oy = ty0 + qy;
  int ox0 = tx0 + qx * 4;
  int hl = qy >> 1;                     // local input row 0..1
  int ix0 = qx * 2;                     // local patch col of f[0]

  // 100 weights for 4 adjacent output pixels, from q-planar wbuf
  int sh = qy & 1;
  int xA = ox0 >> 1;
  int ysrc = oy >> 1;
  const float* wq0 = wbuf + ((size_t)(n * 4 + sh * 2 + 0) * HW + ysrc * 64 + xA) * 25;
  const float* wq1 = wbuf + ((size_t)(n * 4 + sh * 2 + 1) * HW + ysrc * 64 + xA) * 25;
  float wreg[100];
#pragma unroll
  for (int k = 0; k < 25; ++k) {
    wreg[k]      = wq0[k];        // pixel ox0+0: (q=sh*2,   x=xA)
    wreg[25 + k] = wq1[k];        // pixel ox0+1: (q=sh*2+1, x=xA)
    wreg[50 + k] = wq0[25 + k];   // pixel ox0+2: (q=sh*2,   x=xA+1)
    wreg[75 + k] = wq1[25 + k];   // pixel ox0+3: (q=sh*2+1, x=xA+1)
  }

  for (int it = 0; it < 8; ++it) {
    int cl = it * 16 + cslot;
    const float* p = xpatch + cl * 72 + ix0;
    float a0 = 0.f, a1 = 0.f, a2 = 0.f, a3 = 0.f;
#pragma unroll
    for (int i = 0; i < 5; ++i) {
      const float* row = p + (hl + i) * 12;
      float2 f01 = *(const float2*)(row);
      float2 f23 = *(const float2*)(row + 2);
      float2 f45 = *(const float2*)(row + 4);
      float f[6] = {f01.x, f01.y, f23.x, f23.y, f45.x, f45.y};
#pragma unroll
      for (int j = 0; j < 5; ++j) {
        a0 = fmaf(f[j],     wreg[i * 5 + j],      a0);
        a1 = fmaf(f[j],     wreg[25 + i * 5 + j], a1);
        a2 = fmaf(f[j + 1], wreg[50 + i * 5 + j], a2);
        a3 = fmaf(f[j + 1], wreg[75 + i * 5 + j], a3);
      }
    }
    float4 o4 = make_float4(a0, a1, a2, a3);
    *(float4*)(out + (size_t)((n * CI + cg * 128 + cl) * HS + oy) * WS_ + ox0) = o4;
  }
}

// ---------------------------------------------------------------------------
extern "C" void kernel_launch(void* const* d_in, const int* in_sizes, int n_in,
                              void* d_out, int out_size, void* d_ws,
                              size_t ws_size, hipStream_t stream) {
  const float* x      = (const float*)d_in[0];
  const float* w_comp = (const float*)d_in[1];
  const float* b_comp = (const float*)d_in[2];
  const float* w_enc  = (const float*)d_in[3];
  const float* b_enc  = (const float*)d_in[4];
  float* out = (float*)d_out;

  char* ws = (char*)d_ws;
  unsigned short* comp_cl = (unsigned short*)ws;                  // 2,097,152 B
  unsigned short* Aw1     = (unsigned short*)(ws + 2097152);      //    32,768 B
  unsigned short* Aw2     = (unsigned short*)(ws + 2129920);      //   129,024 B
  float*          wbuf_q  = (float*)(ws + 2359296);               // 6,553,600 B

  prep_kernel<<<dim3(316), 256, 0, stream>>>(w_comp, w_enc, Aw1, Aw2);
  conv1x1_mfma<<<dim3(256), 256, 0, stream>>>(x, Aw1, b_comp, comp_cl);
  kenc_mfma<<<dim3(256), 256, 0, stream>>>(comp_cl, Aw2, b_enc, wbuf_q);
  reassembly_kernel<<<dim3(2048), 256, 0, stream>>>(x, wbuf_q, out);
}